// Round 1
// 571.457 us; speedup vs baseline: 1.1377x; 1.1377x over previous
//
#include <hip/hip_runtime.h>
#include <math.h>

// ---------------------------------------------------------------------------
// Round 8: tps_k rewritten — LDS-parallel Gaussian elimination.
//   Previous tps_k ran the 12x14 solve serially on thread 0 with a
//   runtime-indexed private array -> scratch (local mem) -> 113-161 us of
//   pure scratch latency (FETCH 673KB for a 67KB-I/O kernel).
//   Now: M[12][14] in LDS, build/swap/update parallel across the wave,
//   back-sub via 16-lane shfl reduce. Everything else unchanged from R7.
//
//   conv2/3/4: tile_conv single fp16 (full-image grids)
//   corr:      tile_conv SPLIT fp16 (hi+lo, 3xMFMA) -> CORRf fp32 + CORRh hi
//   conv_r1:   tile_conv single fp16, split-K 7
//   conv_r2:   direct gemm_conv single fp16, split-K 25
//   conv1 fp32->fp16 full-image; dense/tps/masksum fp32.
//
// Workspace (float units), peak 124.2 MB (<127.8 MB proven round 5):
//   WT2@0(36864) WT3@36864(147456) WT4@184320(589824)
//   WTr1@774144(802816,single) WTr2@1576960(102400,single)
//   FEATs @1679360 (4194304)   single fp16, 2 img x 8192 x 512
//   S2    @5873664 (8388608)   full img 32x64x64x128 fp16
//   S1    @14262272 (16777216) full img 32x128x128x64 fp16
//   S3    overlays S1 @14262272 (4194304)
//   post-chain: FEATsp @5873664 (8388608, hi+lo; overlays S2)
//     CORRf@14262272(2097152) CORRh@16359424(1048576, single)
//     R1p@17408000(7x409600) R1h@20275200(204800, single)
//     R2p@20480000(25x73728) R2f@22323200(73728)
//     GEO@22396928 AX@22397504 AY@22405696 -> end 22413888
// ---------------------------------------------------------------------------

typedef __attribute__((ext_vector_type(8))) _Float16 f16x8;
typedef __attribute__((ext_vector_type(4))) float f32x4;

__device__ __forceinline__ unsigned short f2h(float f) {
  return __builtin_bit_cast(unsigned short, (_Float16)f);
}
__device__ __forceinline__ float h2f(unsigned short u) {
  return (float)__builtin_bit_cast(_Float16, u);
}

// ---------------------------------------------------------------- weight prep
__global__ __launch_bounds__(256) void wt_single(const float* __restrict__ w,
                                                 unsigned short* __restrict__ wt,
                                                 int K, int C) {
  const int idx = blockIdx.x * 256 + threadIdx.x;
  if (idx < K * C) {
    const int k = idx / C, o = idx % C;
    wt[(size_t)o * K + k] = f2h(w[idx]);
  }
}

// ---------------------------------------------------------------- conv1
__global__ __launch_bounds__(64) void conv1_k(const float* __restrict__ in,
                                              const float* __restrict__ w,
                                              unsigned short* __restrict__ out) {
  const int o = threadIdx.x;
  const int j0 = blockIdx.x * 4;
  const int i = blockIdx.y;
  const int b = blockIdx.z;
  const float* __restrict__ inb = in + (size_t)b * 256 * 256 * 3;
  float acc[4] = {0.f, 0.f, 0.f, 0.f};
  const bool full = (2 * j0 + 8) < 256;
#pragma unroll
  for (int di = 0; di < 3; ++di) {
    const int y = 2 * i + di;
    if (y < 256) {
      const float* __restrict__ row = inb + ((size_t)y * 256 + 2 * j0) * 3;
      float xf[28];
      if (full) {
#pragma unroll
        for (int q = 0; q < 14; ++q) {
          const float2 v = ((const float2*)row)[q];
          xf[2 * q] = v.x; xf[2 * q + 1] = v.y;
        }
      } else {
#pragma unroll
        for (int q = 0; q < 12; ++q) {
          const float2 v = ((const float2*)row)[q];
          xf[2 * q] = v.x; xf[2 * q + 1] = v.y;
        }
        xf[24] = xf[25] = xf[26] = xf[27] = 0.f;
      }
#pragma unroll
      for (int c = 0; c < 3; ++c)
#pragma unroll
        for (int dj = 0; dj < 3; ++dj) {
          const float wv = w[(size_t)(((di * 3 + dj) * 3) + c) * 64 + o];
#pragma unroll
          for (int t = 0; t < 4; ++t) acc[t] += xf[(2 * t + dj) * 3 + c] * wv;
        }
    }
  }
#pragma unroll
  for (int t = 0; t < 4; ++t)
    out[(((size_t)b * 128 + i) * 128 + j0 + t) * 64 + o] = f2h(fmaxf(acc[t], 0.f));
}

// ---------------------------------------------------------------- tile conv
// LDS-tiled implicit-GEMM: out[m][n] = sum_k A[m][k]*Wt[n][k].
// SPLIT: A/B have hi+lo planes (aLo/bLo el offsets), 3 MFMAs per pair.
// SK>1: split-K over taps, fp32 partial slices to outf.
// BATB: B rows batched by A's batch index (corr).
// OUTF32: write fp32 to outf AND single fp16 hi to outh.
template <int BM, int BN, int CIN, int COUT, int KH, int KW, int STRIDE,
          int SAMEPAD, int SPLIT, int SK, int BATB, int OUTF32, int RELU>
__global__ __launch_bounds__(256) void tile_conv(
    const unsigned short* __restrict__ in, const unsigned short* __restrict__ wt,
    unsigned short* __restrict__ outh, float* __restrict__ outf,
    int Hin, int Win, int Hout, int Wout, int aLo, int bLo) {
  constexpr int LDA = 72;
  constexpr int CPT = CIN / 64;
  constexpr int LA = BM / 32;
  constexpr int LB = BN / 32;
  constexpr int KTOT = KH * KW * CIN;
  constexpr int MT = BM / 32;
  constexpr int NT = BN / 32;
  __shared__ _Float16 As[(1 + SPLIT) * BM * LDA];
  __shared__ _Float16 Bs[(1 + SPLIT) * BN * LDA];

  const int t = threadIdx.x;
  const int lane = t & 63, wid = t >> 6;
  const int lrow = lane & 15, quad = lane >> 4;
  const int m0 = blockIdx.x * BM;
  const int n0 = blockIdx.y * BN;

  int pixB[LA], iS[LA], jS[LA], lofA[LA];
#pragma unroll
  for (int i = 0; i < LA; ++i) {
    const int u = t + 256 * i;
    const int r = u >> 3, sl = u & 7;
    const int m = m0 + r;
    const int j = m % Wout;
    const int t2 = m / Wout;
    const int ii = t2 % Hout;
    const int b = t2 / Hout;
    iS[i] = ii * STRIDE;
    jS[i] = j * STRIDE;
    pixB[i] = ((b * Hin + iS[i]) * Win + jS[i]) * CIN + sl * 8;
    lofA[i] = r * LDA + sl * 8;
  }
  const unsigned short* wb = wt;
  if (BATB) wb += (size_t)(m0 / (Hout * Wout)) * COUT * KTOT;
  int bofB[LB], lofB[LB];
#pragma unroll
  for (int i = 0; i < LB; ++i) {
    const int u = t + 256 * i;
    const int r = u >> 3, sl = u & 7;
    bofB[i] = (n0 + r) * KTOT + sl * 8;
    lofB[i] = r * LDA + sl * 8;
  }

  const f16x8 zh = {0, 0, 0, 0, 0, 0, 0, 0};
  f32x4 acc[MT][NT];
#pragma unroll
  for (int mi = 0; mi < MT; ++mi)
#pragma unroll
    for (int ni = 0; ni < NT; ++ni) acc[mi][ni] = {0.f, 0.f, 0.f, 0.f};

  const int mB = (wid >> 1) * (BM / 2);
  const int nB = (wid & 1) * (BN / 2);

  int tap_lo = 0, tap_hi = KH * KW;
  if (SK > 1) {
    tap_lo = (int)blockIdx.z * KH * KW / SK;
    tap_hi = ((int)blockIdx.z + 1) * KH * KW / SK;
  }
  for (int ch = tap_lo * CPT; ch < tap_hi * CPT; ++ch) {
    const int tap = ch / CPT;
    const int c0 = (ch % CPT) * 64;
    const int di = tap / KW, dj = tap % KW;
    const int toff = (di * Win + dj) * CIN + c0;
    const int woff = tap * CIN + c0;
    f16x8 va[LA], vb[LB], va2[LA], vb2[LB];
#pragma unroll
    for (int i = 0; i < LA; ++i) {
      const bool ok = !SAMEPAD || ((iS[i] + di < Hin) && (jS[i] + dj < Win));
      va[i] = ok ? *(const f16x8*)(in + pixB[i] + toff) : zh;
      if (SPLIT) va2[i] = ok ? *(const f16x8*)(in + pixB[i] + toff + aLo) : zh;
    }
#pragma unroll
    for (int i = 0; i < LB; ++i) {
      vb[i] = *(const f16x8*)(wb + bofB[i] + woff);
      if (SPLIT) vb2[i] = *(const f16x8*)(wb + bofB[i] + woff + bLo);
    }
    __syncthreads();
#pragma unroll
    for (int i = 0; i < LA; ++i) {
      *(f16x8*)&As[lofA[i]] = va[i];
      if (SPLIT) *(f16x8*)&As[BM * LDA + lofA[i]] = va2[i];
    }
#pragma unroll
    for (int i = 0; i < LB; ++i) {
      *(f16x8*)&Bs[lofB[i]] = vb[i];
      if (SPLIT) *(f16x8*)&Bs[BN * LDA + lofB[i]] = vb2[i];
    }
    __syncthreads();
#pragma unroll
    for (int ks = 0; ks < 2; ++ks) {
      f16x8 af[MT], bf[NT], al[MT], bl[NT];
#pragma unroll
      for (int mi = 0; mi < MT; ++mi) {
        const int off = (mB + mi * 16 + lrow) * LDA + ks * 32 + quad * 8;
        af[mi] = *(const f16x8*)&As[off];
        if (SPLIT) al[mi] = *(const f16x8*)&As[BM * LDA + off];
      }
#pragma unroll
      for (int ni = 0; ni < NT; ++ni) {
        const int off = (nB + ni * 16 + lrow) * LDA + ks * 32 + quad * 8;
        bf[ni] = *(const f16x8*)&Bs[off];
        if (SPLIT) bl[ni] = *(const f16x8*)&Bs[BN * LDA + off];
      }
#pragma unroll
      for (int mi = 0; mi < MT; ++mi)
#pragma unroll
        for (int ni = 0; ni < NT; ++ni) {
          if (SPLIT) {
            acc[mi][ni] = __builtin_amdgcn_mfma_f32_16x16x32_f16(af[mi], bl[ni],
                                                                 acc[mi][ni], 0, 0, 0);
            acc[mi][ni] = __builtin_amdgcn_mfma_f32_16x16x32_f16(al[mi], bf[ni],
                                                                 acc[mi][ni], 0, 0, 0);
          }
          acc[mi][ni] = __builtin_amdgcn_mfma_f32_16x16x32_f16(af[mi], bf[ni],
                                                               acc[mi][ni], 0, 0, 0);
        }
    }
  }
  const size_t slice =
      (SK > 1) ? (size_t)blockIdx.z * ((size_t)gridDim.x * BM * COUT) : 0;
#pragma unroll
  for (int mi = 0; mi < MT; ++mi)
#pragma unroll
    for (int ni = 0; ni < NT; ++ni)
#pragma unroll
      for (int r = 0; r < 4; ++r) {
        const int row = m0 + mB + mi * 16 + quad * 4 + r;
        const int col = n0 + nB + ni * 16 + lrow;
        const size_t idx = (size_t)row * COUT + col;
        float v = acc[mi][ni][r];
        if (SK > 1) {
          outf[slice + idx] = v;
        } else if (OUTF32) {
          outf[idx] = v;
          outh[idx] = f2h(v);
        } else {
          if (RELU) v = fmaxf(v, 0.f);
          outh[idx] = f2h(v);
        }
      }
}

// ---------------------------------------------------------------- direct MFMA
// kept for conv_r2 (tiny), single plane.
template <int MT, int NT, int CIN, int COUT, int KH, int KW, int SK>
__global__ __launch_bounds__(256) void gemm_conv(
    const unsigned short* __restrict__ in, const unsigned short* __restrict__ wt,
    float* __restrict__ outf, int Hin, int Win, int Hout, int Wout) {
  const int KTOT = KH * KW * CIN;
  const int lane = threadIdx.x & 63;
  const int wid = threadIdx.x >> 6;
  const int lrow = lane & 15;
  const int quad = lane >> 4;
  const int m0 = (blockIdx.x * 4 + wid) * (16 * MT);
  const int n0 = blockIdx.y * (16 * NT);

  int pix[MT];
#pragma unroll
  for (int mi = 0; mi < MT; ++mi) {
    const int m = m0 + mi * 16 + lrow;
    const int j = m % Wout;
    const int t = m / Wout;
    const int i = t % Hout;
    const int b = t / Hout;
    pix[mi] = (b * Hin + i) * Win + j;
  }
  const unsigned short* brow[NT];
#pragma unroll
  for (int ni = 0; ni < NT; ++ni)
    brow[ni] = wt + (size_t)(n0 + ni * 16 + lrow) * KTOT + quad * 8;

  f32x4 acc[MT][NT];
#pragma unroll
  for (int mi = 0; mi < MT; ++mi)
#pragma unroll
    for (int ni = 0; ni < NT; ++ni) acc[mi][ni] = {0.f, 0.f, 0.f, 0.f};

  const int tap_lo = (int)blockIdx.z * KH * KW / SK;
  const int tap_hi = ((int)blockIdx.z + 1) * KH * KW / SK;
  for (int tap = tap_lo; tap < tap_hi; ++tap) {
    const int di = tap / KW, dj = tap % KW;
    const unsigned short* ap[MT];
#pragma unroll
    for (int mi = 0; mi < MT; ++mi)
      ap[mi] = in + ((size_t)pix[mi] + di * Win + dj) * CIN + quad * 8;
    const int ko = tap * CIN;
#pragma unroll
    for (int c0 = 0; c0 < CIN; c0 += 32) {
      f16x8 ah[MT], bh[NT];
#pragma unroll
      for (int mi = 0; mi < MT; ++mi) ah[mi] = *(const f16x8*)(ap[mi] + c0);
#pragma unroll
      for (int ni = 0; ni < NT; ++ni) bh[ni] = *(const f16x8*)(brow[ni] + ko + c0);
#pragma unroll
      for (int mi = 0; mi < MT; ++mi)
#pragma unroll
        for (int ni = 0; ni < NT; ++ni)
          acc[mi][ni] = __builtin_amdgcn_mfma_f32_16x16x32_f16(ah[mi], bh[ni],
                                                               acc[mi][ni], 0, 0, 0);
    }
  }
  const size_t slice = (size_t)blockIdx.z * ((size_t)gridDim.x * 64 * MT * COUT);
#pragma unroll
  for (int mi = 0; mi < MT; ++mi)
#pragma unroll
    for (int ni = 0; ni < NT; ++ni)
#pragma unroll
      for (int r = 0; r < 4; ++r) {
        const int row = m0 + mi * 16 + quad * 4 + r;
        const int col = n0 + ni * 16 + lrow;
        outf[slice + (size_t)row * COUT + col] = acc[mi][ni][r];
      }
}

// ---------------------------------------------------------------- split-K epi
__global__ __launch_bounds__(256) void sum_relu_s(const float* __restrict__ p,
                                                  unsigned short* __restrict__ o,
                                                  int n, int parts) {
  const int idx = blockIdx.x * 256 + threadIdx.x;
  if (idx < n) {
    float v = 0.f;
    for (int s = 0; s < parts; ++s) v += p[(size_t)s * n + idx];
    o[idx] = f2h(fmaxf(v, 0.f));
  }
}
__global__ __launch_bounds__(256) void sum_relu_f(const float* __restrict__ p,
                                                  float* __restrict__ o,
                                                  int n, int parts) {
  const int idx = blockIdx.x * 256 + threadIdx.x;
  if (idx < n) {
    float v = 0.f;
    for (int s = 0; s < parts; ++s) v += p[(size_t)s * n + idx];
    o[idx] = fmaxf(v, 0.f);
  }
}

// ---------------------------------------------------------------- l2 normalize
// in: single fp16; out: split pair (hi @y, lo @y+loOff).
__global__ __launch_bounds__(64) void l2norm_k(const unsigned short* __restrict__ x,
                                               unsigned short* __restrict__ y,
                                               int loOff) {
  const int lane = threadIdx.x;
  const f16x8 v = *(const f16x8*)(x + (size_t)blockIdx.x * 512 + lane * 8);
  float f[8];
  float s = 0.f;
#pragma unroll
  for (int k = 0; k < 8; ++k) {
    f[k] = (float)v[k];
    s += f[k] * f[k];
  }
#pragma unroll
  for (int off = 32; off; off >>= 1) s += __shfl_xor(s, off, 64);
  const float inv = 1.f / (sqrtf(s) + 1e-6f);
  f16x8 vh, vl;
#pragma unroll
  for (int k = 0; k < 8; ++k) {
    const float nv = f[k] * inv;
    const _Float16 hi = (_Float16)nv;
    vh[k] = hi;
    vl[k] = (_Float16)(nv - (float)hi);
  }
  unsigned short* ph = y + (size_t)blockIdx.x * 512 + lane * 8;
  *(f16x8*)ph = vh;
  *(f16x8*)(ph + (size_t)loOff) = vl;
}

// ---------------------------------------------------------------- dense
__global__ __launch_bounds__(64) void dense_k(const float* __restrict__ r2,
                                              const float* __restrict__ wd,
                                              const float* __restrict__ bd,
                                              float* __restrict__ geo) {
  const int o = blockIdx.x;
  const int b = blockIdx.y;
  const int lane = threadIdx.x;
  const float* __restrict__ rb = r2 + (size_t)b * 2304;
  float s = 0.f;
  for (int k = lane; k < 2304; k += 64) s += rb[k] * wd[(size_t)k * 18 + o];
#pragma unroll
  for (int off = 32; off; off >>= 1) s += __shfl_xor(s, off, 64);
  if (lane == 0) geo[b * 18 + o] = s + bd[o];
}

// ---------------------------------------------------------------- TPS
// Round 8: LDS-parallel version. One block (1 wave) per batch.
// The 12x14 augmented system lives in LDS; build, pivot-swap and the
// rank-1 elimination updates are spread across the wave. Back-sub uses
// 16-lane shfl tree reduces (lanes 0-15: x, lanes 16-31: y).
__device__ __forceinline__ float tps_u(float r) { return r * r * logf(r + 1e-6f); }

__global__ __launch_bounds__(64) void tps_k(const float* __restrict__ geo,
                                            float* __restrict__ axb,
                                            float* __restrict__ ayb) {
  const int b = blockIdx.x;
  const int tid = threadIdx.x;
  __shared__ float M[12][14];
  __shared__ float fel[12];
  __shared__ float dxs[9], dys[9];
  __shared__ float th[2][12];   // [0]=x theta, [1]=y theta
  __shared__ float sW[2][9];
  __shared__ float sA[2][3];
  __shared__ int sPiv;

  const float srcx[9] = {0.f, 0.5f, 1.f, 0.f, 0.5f, 1.f, 0.f, 5.f, 1.f};
  const float srcy[9] = {0.f, 0.f, 0.f, 0.5f, 0.5f, 0.5f, 1.f, 1.f, 1.f};

  // dst points + RHS columns (12,13)
  if (tid < 9) {
    const float mx = geo[b * 18 + 2 * tid], my = geo[b * 18 + 2 * tid + 1];
    dxs[tid] = srcx[tid] + mx;
    dys[tid] = srcy[tid] + my;
    M[tid][12] = -mx;
    M[tid][13] = -my;
  } else if (tid < 12) {
    M[tid][12] = 0.f;
    M[tid][13] = 0.f;
  }
  __syncthreads();
  // K block: 81 tps_u entries in parallel
  for (int e = tid; e < 81; e += 64) {
    const int p = e / 9, q = e % 9;
    const float ddx = dxs[p] - dxs[q], ddy = dys[p] - dys[q];
    const float r = sqrtf(ddx * ddx + ddy * ddy + 1e-12f);
    M[p][q] = tps_u(r);
  }
  // P blocks + zero bottom-right 3x3
  if (tid < 9) {
    M[tid][9] = 1.f;  M[tid][10] = dxs[tid]; M[tid][11] = dys[tid];
    M[9][tid] = 1.f;  M[10][tid] = dxs[tid]; M[11][tid] = dys[tid];
  } else if (tid < 12) {
    M[tid][9] = 0.f; M[tid][10] = 0.f; M[tid][11] = 0.f;
  }
  __syncthreads();

  // Gaussian elimination with partial pivoting (same arithmetic/order as R7)
  for (int k = 0; k < 12; ++k) {
    if (tid == 0) {
      int piv = k;
      float best = fabsf(M[k][k]);
      for (int r = k + 1; r < 12; ++r) {
        const float v = fabsf(M[r][k]);
        if (v > best) { best = v; piv = r; }
      }
      sPiv = piv;
    }
    __syncthreads();
    const int piv = sPiv;
    if (piv != k && tid < 14) {
      const float tmp = M[k][tid];
      M[k][tid] = M[piv][tid];
      M[piv][tid] = tmp;
    }
    __syncthreads();
    if (tid > k && tid < 12) fel[tid] = M[tid][k] / M[k][k];
    __syncthreads();
    for (int e = tid; e < (11 - k) * 14; e += 64) {
      const int r = k + 1 + e / 14, cc = e % 14;
      if (cc >= k) M[r][cc] -= fel[r] * M[k][cc];
    }
    __syncthreads();
  }

  // Back substitution: lanes 0-15 -> x (RHS col 12), lanes 16-31 -> y (col 13)
  const int grp = tid >> 4;
  const int cc = tid & 15;
  for (int k = 11; k >= 0; --k) {
    float prod = 0.f;
    if (grp < 2 && cc > k && cc < 12) prod = M[k][cc] * th[grp][cc];
#pragma unroll
    for (int off = 8; off; off >>= 1) prod += __shfl_xor(prod, off, 16);
    if (grp < 2 && cc == 0) th[grp][k] = (M[k][12 + grp] - prod) / M[k][k];
    __syncthreads();
  }

  // w/a extraction: w[0] = -sum(theta[1..8]), w[p]=theta[p], a = theta[9..11]
  if (tid < 2) {
    float sw = 0.f;
    for (int p = 1; p < 9; ++p) {
      sW[tid][p] = th[tid][p];
      sw += th[tid][p];
    }
    sW[tid][0] = -sw;
    sA[tid][0] = th[tid][9];
    sA[tid][1] = th[tid][10];
    sA[tid][2] = th[tid][11];
  }
  __syncthreads();

  // evaluate warp field on the 16x16 grid (4 points per lane)
  for (int p = tid; p < 256; p += 64) {
    const int pi = p >> 4, pj = p & 15;
    const float x = pj * (1.f / 15.f), y = pi * (1.f / 15.f);
    float zx = sA[0][0] + x * sA[0][1] + y * sA[0][2];
    float zy = sA[1][0] + x * sA[1][1] + y * sA[1][2];
#pragma unroll
    for (int c = 0; c < 9; ++c) {
      const float ddx = x - dxs[c], ddy = y - dys[c];
      const float r = sqrtf(ddx * ddx + ddy * ddy + 1e-12f);
      const float u = tps_u(r);
      zx += u * sW[0][c];
      zy += u * sW[1][c];
    }
    axb[b * 256 + p] = (x + zx) * 15.f;
    ayb[b * 256 + p] = (y + zy) * 15.f;
  }
}

// ---------------------------------------------------------------- masked sum
__global__ __launch_bounds__(256) void masksum_k(const float* __restrict__ corr,
                                                 const float* __restrict__ axb,
                                                 const float* __restrict__ ayb,
                                                 float* __restrict__ out) {
  const int b = blockIdx.x;
  const int pB = threadIdx.x;
  const float ax = axb[b * 256 + pB];
  const float ay = ayb[b * 256 + pB];
  const float* __restrict__ cb = corr + (size_t)b * 65536;
  float s = 0.f;
  for (int i = 0; i < 16; ++i) {
    if (fabsf((float)i - ay) <= 1.0f) {
      const float* __restrict__ ci = cb + (size_t)i * 16 * 256 + pB;
      for (int j = 0; j < 16; ++j) {
        if (fabsf((float)j - ax) <= 1.0f) s += ci[(size_t)j * 256];
      }
    }
  }
  __shared__ float sm[256];
  sm[pB] = s;
  __syncthreads();
  for (int off = 128; off; off >>= 1) {
    if (pB < off) sm[pB] += sm[pB + off];
    __syncthreads();
  }
  if (pB == 0) out[b] = sm[0];
}

// ---------------------------------------------------------------- launch
extern "C" void kernel_launch(void* const* d_in, const int* in_sizes, int n_in,
                              void* d_out, int out_size, void* d_ws, size_t ws_size,
                              hipStream_t stream) {
  const float* imgA = (const float*)d_in[0];
  const float* imgB = (const float*)d_in[1];
  const float* W1 = (const float*)d_in[2];
  const float* W2 = (const float*)d_in[3];
  const float* W3 = (const float*)d_in[4];
  const float* W4 = (const float*)d_in[5];
  const float* Wr1 = (const float*)d_in[6];
  const float* Wr2 = (const float*)d_in[7];
  const float* Wd = (const float*)d_in[8];
  const float* bd = (const float*)d_in[9];

  float* ws = (float*)d_ws;
  unsigned short* WT2 = (unsigned short*)(ws + 0);
  unsigned short* WT3 = (unsigned short*)(ws + 36864);
  unsigned short* WT4 = (unsigned short*)(ws + 184320);
  unsigned short* WTr1 = (unsigned short*)(ws + 774144);
  unsigned short* WTr2 = (unsigned short*)(ws + 1576960);
  unsigned short* FEATs = (unsigned short*)(ws + 1679360);
  unsigned short* S2 = (unsigned short*)(ws + 5873664);
  unsigned short* S1 = (unsigned short*)(ws + 14262272);
  unsigned short* S3 = (unsigned short*)(ws + 14262272);    // overlays S1
  unsigned short* FEATsp = (unsigned short*)(ws + 5873664); // overlays S2
  float* CORRf = ws + 14262272;                             // overlays S1/S3
  unsigned short* CORRh = (unsigned short*)(ws + 16359424);
  float* R1p = ws + 17408000;
  unsigned short* R1h = (unsigned short*)(ws + 20275200);
  float* R2p = ws + 20480000;
  float* R2f = ws + 22323200;
  float* GEOb = ws + 22396928;
  float* AXb = ws + 22397504;
  float* AYb = ws + 22405696;

  // weight prep (all single-plane)
  wt_single<<<288, 256, 0, stream>>>(W2, WT2, 576, 128);
  wt_single<<<1152, 256, 0, stream>>>(W3, WT3, 1152, 256);
  wt_single<<<4608, 256, 0, stream>>>(W4, WT4, 2304, 512);
  wt_single<<<6272, 256, 0, stream>>>(Wr1, WTr1, 12544, 128);
  wt_single<<<800, 256, 0, stream>>>(Wr2, WTr2, 3200, 64);

  for (int img = 0; img < 2; ++img) {
    const float* src = img ? imgB : imgA;
    conv1_k<<<dim3(32, 128, 32), 64, 0, stream>>>(src, W1, S1);
    // conv2: M = 32*4096 = 131072 -> 1024 blocks of 128x128
    tile_conv<128, 128, 64, 128, 3, 3, 2, 1, 0, 1, 0, 0, 1>
        <<<dim3(1024, 1), 256, 0, stream>>>(S1, WT2, S2, nullptr,
                                            128, 128, 64, 64, 0, 0);
    // conv3: M = 32768 -> 256x2
    tile_conv<128, 128, 128, 256, 3, 3, 2, 1, 0, 1, 0, 0, 1>
        <<<dim3(256, 2), 256, 0, stream>>>(S2, WT3, S3, nullptr,
                                           64, 64, 32, 32, 0, 0);
    // conv4: M = 8192 -> 128x4 of 64x128
    tile_conv<64, 128, 256, 512, 3, 3, 2, 1, 0, 1, 0, 0, 1>
        <<<dim3(128, 4), 256, 0, stream>>>(S3, WT4, FEATs + (size_t)img * 4194304,
                                           nullptr, 32, 32, 16, 16, 0, 0);
  }

  // l2norm: FEATs (single) -> FEATsp (split pair, lo at +8388608 el)
  l2norm_k<<<16384, 64, 0, stream>>>(FEATs, FEATsp, 8388608);
  // corr: tiled split GEMM (batched B), fp32 out + single fp16 hi out
  tile_conv<64, 64, 512, 256, 1, 1, 1, 0, 1, 1, 1, 1, 0>
      <<<dim3(128, 4), 256, 0, stream>>>(FEATsp, FEATsp + 4194304, CORRh, CORRf,
                                         16, 16, 16, 16, 8388608, 8388608);
  // conv_r1: tiled single fp16, split-K 7 -> fp32 partials
  tile_conv<64, 128, 256, 128, 7, 7, 1, 0, 0, 7, 0, 0, 0>
      <<<dim3(50, 1, 7), 256, 0, stream>>>(CORRh, WTr1, nullptr, R1p,
                                           16, 16, 10, 10, 0, 0);
  sum_relu_s<<<1600, 256, 0, stream>>>(R1p, R1h, 409600, 7);
  // conv_r2: direct single fp16, split-K 25
  gemm_conv<1, 4, 128, 64, 5, 5, 25>
      <<<dim3(18, 1, 25), 256, 0, stream>>>(R1h, WTr2, R2p, 10, 10, 6, 6);
  sum_relu_f<<<288, 256, 0, stream>>>(R2p, R2f, 73728, 25);
  dense_k<<<dim3(18, 32), 64, 0, stream>>>(R2f, Wd, bd, GEOb);
  tps_k<<<32, 64, 0, stream>>>(GEOb, AXb, AYb);
  masksum_k<<<32, 256, 0, stream>>>(CORRf, AXb, AYb, (float*)d_out);
}

// Round 2
// 498.460 us; speedup vs baseline: 1.3043x; 1.1464x over previous
//
#include <hip/hip_runtime.h>
#include <math.h>

// ---------------------------------------------------------------------------
// Round 9: conv1 -> MFMA implicit GEMM.
//   R8 conv1_k was scalar fp32 VALU (77us/img, VALUBusy 42%, HBM 17%).
//   conv1 is GEMM M=32*128*128, N=64, K=27 (3x3x3) padded to 32 -> exactly
//   one 16x16x32 f16 MFMA per tile. conv1_mfma: 1 block per (out-row,batch),
//   stage 3 input rows fp32->fp16 in LDS (coalesced), per-lane im2col gather
//   for A-frags, B-frags from K-padded WT1[64][32], fused ReLU.
//   Memory floor ~17us/img (104MB traffic at 6.3TB/s).
//
//   tps_k: LDS-parallel Gaussian elimination (R8).
//   conv2/3/4: tile_conv single fp16 (full-image grids)
//   corr:      tile_conv SPLIT fp16 (hi+lo, 3xMFMA) -> CORRf fp32 + CORRh hi
//   conv_r1:   tile_conv single fp16, split-K 7
//   conv_r2:   direct gemm_conv single fp16, split-K 25
//   dense/tps/masksum fp32.
//
// Workspace (float units), peak 124.16 MB (<127.8 MB proven round 5):
//   WT2@0(36864) WT3@36864(147456) WT4@184320(589824)
//   WTr1@774144(802816,single) WTr2@1576960(102400,single)
//   FEATs @1679360 (4194304)   single fp16, 2 img x 8192 x 512
//   S2    @5873664 (8388608)   full img 32x64x64x128 fp16
//   S1    @14262272 (16777216) full img 32x128x128x64 fp16
//   S3    overlays S1 @14262272 (4194304)
//   post-chain: FEATsp @5873664 (8388608, hi+lo; overlays S2)
//     CORRf@14262272(2097152) CORRh@16359424(1048576, single)
//     R1p@17408000(7x409600) R1h@20275200(204800, single)
//     R2p@20480000(25x73728) R2f@22323200(73728)
//     GEO@22396928 AX@22397504 AY@22405696 -> end 22413888
//   WT1@31039488 (1024)  -- after S1 end, avoids overlay collision
// ---------------------------------------------------------------------------

typedef __attribute__((ext_vector_type(8))) _Float16 f16x8;
typedef __attribute__((ext_vector_type(4))) float f32x4;

__device__ __forceinline__ unsigned short f2h(float f) {
  return __builtin_bit_cast(unsigned short, (_Float16)f);
}
__device__ __forceinline__ float h2f(unsigned short u) {
  return (float)__builtin_bit_cast(_Float16, u);
}

// ---------------------------------------------------------------- weight prep
__global__ __launch_bounds__(256) void wt_single(const float* __restrict__ w,
                                                 unsigned short* __restrict__ wt,
                                                 int K, int C) {
  const int idx = blockIdx.x * 256 + threadIdx.x;
  if (idx < K * C) {
    const int k = idx / C, o = idx % C;
    wt[(size_t)o * K + k] = f2h(w[idx]);
  }
}

// WT1: [64 out][32 k] fp16, k = (di*3+dj)*3+c for k<27, zero-padded to 32.
__global__ __launch_bounds__(256) void wt1_prep(const float* __restrict__ w,
                                                unsigned short* __restrict__ wt) {
  const int idx = blockIdx.x * 256 + threadIdx.x;  // 64*32 = 2048
  if (idx < 2048) {
    const int o = idx >> 5, k = idx & 31;
    wt[idx] = (k < 27) ? f2h(w[(size_t)k * 64 + o]) : (unsigned short)0;
  }
}

// ---------------------------------------------------------------- conv1 MFMA
// One block per (output row i, batch b). 256 threads = 4 waves.
// Wave w computes rows j = w*32..w*32+31 (MT=2) x all 64 channels (NT=4).
// K = 32 (27 real taps + 5 zero pad) -> single MFMA per 16x16 tile.
__global__ __launch_bounds__(256) void conv1_mfma(const float* __restrict__ in,
                                                  const unsigned short* __restrict__ wt1,
                                                  unsigned short* __restrict__ out) {
  const int i = blockIdx.x;   // output row 0..127
  const int b = blockIdx.y;   // batch 0..31
  const int tid = threadIdx.x;
  const int lane = tid & 63, wid = tid >> 6;
  const int lrow = lane & 15, quad = lane >> 4;

  // Rows[di][x*3+c], x in 0..256 (x=256 is SAME right-pad, zero)
  __shared__ _Float16 Rows[3][771];

  const float* __restrict__ inb = in + (size_t)b * 196608;  // 256*256*3
#pragma unroll
  for (int di = 0; di < 3; ++di) {
    const int y = 2 * i + di;
    if (y < 256) {
      const float* __restrict__ row = inb + (size_t)y * 768;
      for (int e = tid; e < 768; e += 256) Rows[di][e] = (_Float16)row[e];
    } else {
      for (int e = tid; e < 768; e += 256) Rows[di][e] = (_Float16)0.f;
    }
    if (tid < 3) Rows[di][768 + tid] = (_Float16)0.f;
  }
  __syncthreads();

  // B fragments: all 64 cols, straight from WT1[64][32]
  f16x8 bf[4];
#pragma unroll
  for (int ni = 0; ni < 4; ++ni)
    bf[ni] = *(const f16x8*)(wt1 + (ni * 16 + lrow) * 32 + quad * 8);

  // A fragments: im2col gather from staged rows.
  // k = quad*8+s -> tap = k/3? no: k = (di*3+dj)*3 + c -> di=k/9, dj=(k/3)%3, c=k%3
  f16x8 af[2];
#pragma unroll
  for (int mi = 0; mi < 2; ++mi) {
    const int j = wid * 32 + mi * 16 + lrow;
#pragma unroll
    for (int s = 0; s < 8; ++s) {
      const int k = quad * 8 + s;
      if (k < 27) {
        const int di = k / 9, dj = (k / 3) % 3, c = k % 3;
        af[mi][s] = Rows[di][(2 * j + dj) * 3 + c];
      } else {
        af[mi][s] = (_Float16)0.f;
      }
    }
  }

  f32x4 acc[2][4];
#pragma unroll
  for (int mi = 0; mi < 2; ++mi)
#pragma unroll
    for (int ni = 0; ni < 4; ++ni) {
      const f32x4 z = {0.f, 0.f, 0.f, 0.f};
      acc[mi][ni] = __builtin_amdgcn_mfma_f32_16x16x32_f16(af[mi], bf[ni], z, 0, 0, 0);
    }

  // epilogue: row = quad*4+r, col = lrow (tile_conv layout), fused ReLU
  unsigned short* __restrict__ ob = out + (((size_t)b * 128 + i) * 128) * 64;
#pragma unroll
  for (int mi = 0; mi < 2; ++mi)
#pragma unroll
    for (int ni = 0; ni < 4; ++ni)
#pragma unroll
      for (int r = 0; r < 4; ++r) {
        const int j = wid * 32 + mi * 16 + quad * 4 + r;
        const int col = ni * 16 + lrow;
        ob[(size_t)j * 64 + col] = f2h(fmaxf(acc[mi][ni][r], 0.f));
      }
}

// ---------------------------------------------------------------- tile conv
// LDS-tiled implicit-GEMM: out[m][n] = sum_k A[m][k]*Wt[n][k].
// SPLIT: A/B have hi+lo planes (aLo/bLo el offsets), 3 MFMAs per pair.
// SK>1: split-K over taps, fp32 partial slices to outf.
// BATB: B rows batched by A's batch index (corr).
// OUTF32: write fp32 to outf AND single fp16 hi to outh.
template <int BM, int BN, int CIN, int COUT, int KH, int KW, int STRIDE,
          int SAMEPAD, int SPLIT, int SK, int BATB, int OUTF32, int RELU>
__global__ __launch_bounds__(256) void tile_conv(
    const unsigned short* __restrict__ in, const unsigned short* __restrict__ wt,
    unsigned short* __restrict__ outh, float* __restrict__ outf,
    int Hin, int Win, int Hout, int Wout, int aLo, int bLo) {
  constexpr int LDA = 72;
  constexpr int CPT = CIN / 64;
  constexpr int LA = BM / 32;
  constexpr int LB = BN / 32;
  constexpr int KTOT = KH * KW * CIN;
  constexpr int MT = BM / 32;
  constexpr int NT = BN / 32;
  __shared__ _Float16 As[(1 + SPLIT) * BM * LDA];
  __shared__ _Float16 Bs[(1 + SPLIT) * BN * LDA];

  const int t = threadIdx.x;
  const int lane = t & 63, wid = t >> 6;
  const int lrow = lane & 15, quad = lane >> 4;
  const int m0 = blockIdx.x * BM;
  const int n0 = blockIdx.y * BN;

  int pixB[LA], iS[LA], jS[LA], lofA[LA];
#pragma unroll
  for (int i = 0; i < LA; ++i) {
    const int u = t + 256 * i;
    const int r = u >> 3, sl = u & 7;
    const int m = m0 + r;
    const int j = m % Wout;
    const int t2 = m / Wout;
    const int ii = t2 % Hout;
    const int b = t2 / Hout;
    iS[i] = ii * STRIDE;
    jS[i] = j * STRIDE;
    pixB[i] = ((b * Hin + iS[i]) * Win + jS[i]) * CIN + sl * 8;
    lofA[i] = r * LDA + sl * 8;
  }
  const unsigned short* wb = wt;
  if (BATB) wb += (size_t)(m0 / (Hout * Wout)) * COUT * KTOT;
  int bofB[LB], lofB[LB];
#pragma unroll
  for (int i = 0; i < LB; ++i) {
    const int u = t + 256 * i;
    const int r = u >> 3, sl = u & 7;
    bofB[i] = (n0 + r) * KTOT + sl * 8;
    lofB[i] = r * LDA + sl * 8;
  }

  const f16x8 zh = {0, 0, 0, 0, 0, 0, 0, 0};
  f32x4 acc[MT][NT];
#pragma unroll
  for (int mi = 0; mi < MT; ++mi)
#pragma unroll
    for (int ni = 0; ni < NT; ++ni) acc[mi][ni] = {0.f, 0.f, 0.f, 0.f};

  const int mB = (wid >> 1) * (BM / 2);
  const int nB = (wid & 1) * (BN / 2);

  int tap_lo = 0, tap_hi = KH * KW;
  if (SK > 1) {
    tap_lo = (int)blockIdx.z * KH * KW / SK;
    tap_hi = ((int)blockIdx.z + 1) * KH * KW / SK;
  }
  for (int ch = tap_lo * CPT; ch < tap_hi * CPT; ++ch) {
    const int tap = ch / CPT;
    const int c0 = (ch % CPT) * 64;
    const int di = tap / KW, dj = tap % KW;
    const int toff = (di * Win + dj) * CIN + c0;
    const int woff = tap * CIN + c0;
    f16x8 va[LA], vb[LB], va2[LA], vb2[LB];
#pragma unroll
    for (int i = 0; i < LA; ++i) {
      const bool ok = !SAMEPAD || ((iS[i] + di < Hin) && (jS[i] + dj < Win));
      va[i] = ok ? *(const f16x8*)(in + pixB[i] + toff) : zh;
      if (SPLIT) va2[i] = ok ? *(const f16x8*)(in + pixB[i] + toff + aLo) : zh;
    }
#pragma unroll
    for (int i = 0; i < LB; ++i) {
      vb[i] = *(const f16x8*)(wb + bofB[i] + woff);
      if (SPLIT) vb2[i] = *(const f16x8*)(wb + bofB[i] + woff + bLo);
    }
    __syncthreads();
#pragma unroll
    for (int i = 0; i < LA; ++i) {
      *(f16x8*)&As[lofA[i]] = va[i];
      if (SPLIT) *(f16x8*)&As[BM * LDA + lofA[i]] = va2[i];
    }
#pragma unroll
    for (int i = 0; i < LB; ++i) {
      *(f16x8*)&Bs[lofB[i]] = vb[i];
      if (SPLIT) *(f16x8*)&Bs[BN * LDA + lofB[i]] = vb2[i];
    }
    __syncthreads();
#pragma unroll
    for (int ks = 0; ks < 2; ++ks) {
      f16x8 af[MT], bf[NT], al[MT], bl[NT];
#pragma unroll
      for (int mi = 0; mi < MT; ++mi) {
        const int off = (mB + mi * 16 + lrow) * LDA + ks * 32 + quad * 8;
        af[mi] = *(const f16x8*)&As[off];
        if (SPLIT) al[mi] = *(const f16x8*)&As[BM * LDA + off];
      }
#pragma unroll
      for (int ni = 0; ni < NT; ++ni) {
        const int off = (nB + ni * 16 + lrow) * LDA + ks * 32 + quad * 8;
        bf[ni] = *(const f16x8*)&Bs[off];
        if (SPLIT) bl[ni] = *(const f16x8*)&Bs[BN * LDA + off];
      }
#pragma unroll
      for (int mi = 0; mi < MT; ++mi)
#pragma unroll
        for (int ni = 0; ni < NT; ++ni) {
          if (SPLIT) {
            acc[mi][ni] = __builtin_amdgcn_mfma_f32_16x16x32_f16(af[mi], bl[ni],
                                                                 acc[mi][ni], 0, 0, 0);
            acc[mi][ni] = __builtin_amdgcn_mfma_f32_16x16x32_f16(al[mi], bf[ni],
                                                                 acc[mi][ni], 0, 0, 0);
          }
          acc[mi][ni] = __builtin_amdgcn_mfma_f32_16x16x32_f16(af[mi], bf[ni],
                                                               acc[mi][ni], 0, 0, 0);
        }
    }
  }
  const size_t slice =
      (SK > 1) ? (size_t)blockIdx.z * ((size_t)gridDim.x * BM * COUT) : 0;
#pragma unroll
  for (int mi = 0; mi < MT; ++mi)
#pragma unroll
    for (int ni = 0; ni < NT; ++ni)
#pragma unroll
      for (int r = 0; r < 4; ++r) {
        const int row = m0 + mB + mi * 16 + quad * 4 + r;
        const int col = n0 + nB + ni * 16 + lrow;
        const size_t idx = (size_t)row * COUT + col;
        float v = acc[mi][ni][r];
        if (SK > 1) {
          outf[slice + idx] = v;
        } else if (OUTF32) {
          outf[idx] = v;
          outh[idx] = f2h(v);
        } else {
          if (RELU) v = fmaxf(v, 0.f);
          outh[idx] = f2h(v);
        }
      }
}

// ---------------------------------------------------------------- direct MFMA
// kept for conv_r2 (tiny), single plane.
template <int MT, int NT, int CIN, int COUT, int KH, int KW, int SK>
__global__ __launch_bounds__(256) void gemm_conv(
    const unsigned short* __restrict__ in, const unsigned short* __restrict__ wt,
    float* __restrict__ outf, int Hin, int Win, int Hout, int Wout) {
  const int KTOT = KH * KW * CIN;
  const int lane = threadIdx.x & 63;
  const int wid = threadIdx.x >> 6;
  const int lrow = lane & 15;
  const int quad = lane >> 4;
  const int m0 = (blockIdx.x * 4 + wid) * (16 * MT);
  const int n0 = blockIdx.y * (16 * NT);

  int pix[MT];
#pragma unroll
  for (int mi = 0; mi < MT; ++mi) {
    const int m = m0 + mi * 16 + lrow;
    const int j = m % Wout;
    const int t = m / Wout;
    const int i = t % Hout;
    const int b = t / Hout;
    pix[mi] = (b * Hin + i) * Win + j;
  }
  const unsigned short* brow[NT];
#pragma unroll
  for (int ni = 0; ni < NT; ++ni)
    brow[ni] = wt + (size_t)(n0 + ni * 16 + lrow) * KTOT + quad * 8;

  f32x4 acc[MT][NT];
#pragma unroll
  for (int mi = 0; mi < MT; ++mi)
#pragma unroll
    for (int ni = 0; ni < NT; ++ni) acc[mi][ni] = {0.f, 0.f, 0.f, 0.f};

  const int tap_lo = (int)blockIdx.z * KH * KW / SK;
  const int tap_hi = ((int)blockIdx.z + 1) * KH * KW / SK;
  for (int tap = tap_lo; tap < tap_hi; ++tap) {
    const int di = tap / KW, dj = tap % KW;
    const unsigned short* ap[MT];
#pragma unroll
    for (int mi = 0; mi < MT; ++mi)
      ap[mi] = in + ((size_t)pix[mi] + di * Win + dj) * CIN + quad * 8;
    const int ko = tap * CIN;
#pragma unroll
    for (int c0 = 0; c0 < CIN; c0 += 32) {
      f16x8 ah[MT], bh[NT];
#pragma unroll
      for (int mi = 0; mi < MT; ++mi) ah[mi] = *(const f16x8*)(ap[mi] + c0);
#pragma unroll
      for (int ni = 0; ni < NT; ++ni) bh[ni] = *(const f16x8*)(brow[ni] + ko + c0);
#pragma unroll
      for (int mi = 0; mi < MT; ++mi)
#pragma unroll
        for (int ni = 0; ni < NT; ++ni)
          acc[mi][ni] = __builtin_amdgcn_mfma_f32_16x16x32_f16(ah[mi], bh[ni],
                                                               acc[mi][ni], 0, 0, 0);
    }
  }
  const size_t slice = (size_t)blockIdx.z * ((size_t)gridDim.x * 64 * MT * COUT);
#pragma unroll
  for (int mi = 0; mi < MT; ++mi)
#pragma unroll
    for (int ni = 0; ni < NT; ++ni)
#pragma unroll
      for (int r = 0; r < 4; ++r) {
        const int row = m0 + mi * 16 + quad * 4 + r;
        const int col = n0 + ni * 16 + lrow;
        outf[slice + (size_t)row * COUT + col] = acc[mi][ni][r];
      }
}

// ---------------------------------------------------------------- split-K epi
__global__ __launch_bounds__(256) void sum_relu_s(const float* __restrict__ p,
                                                  unsigned short* __restrict__ o,
                                                  int n, int parts) {
  const int idx = blockIdx.x * 256 + threadIdx.x;
  if (idx < n) {
    float v = 0.f;
    for (int s = 0; s < parts; ++s) v += p[(size_t)s * n + idx];
    o[idx] = f2h(fmaxf(v, 0.f));
  }
}
__global__ __launch_bounds__(256) void sum_relu_f(const float* __restrict__ p,
                                                  float* __restrict__ o,
                                                  int n, int parts) {
  const int idx = blockIdx.x * 256 + threadIdx.x;
  if (idx < n) {
    float v = 0.f;
    for (int s = 0; s < parts; ++s) v += p[(size_t)s * n + idx];
    o[idx] = fmaxf(v, 0.f);
  }
}

// ---------------------------------------------------------------- l2 normalize
// in: single fp16; out: split pair (hi @y, lo @y+loOff).
__global__ __launch_bounds__(64) void l2norm_k(const unsigned short* __restrict__ x,
                                               unsigned short* __restrict__ y,
                                               int loOff) {
  const int lane = threadIdx.x;
  const f16x8 v = *(const f16x8*)(x + (size_t)blockIdx.x * 512 + lane * 8);
  float f[8];
  float s = 0.f;
#pragma unroll
  for (int k = 0; k < 8; ++k) {
    f[k] = (float)v[k];
    s += f[k] * f[k];
  }
#pragma unroll
  for (int off = 32; off; off >>= 1) s += __shfl_xor(s, off, 64);
  const float inv = 1.f / (sqrtf(s) + 1e-6f);
  f16x8 vh, vl;
#pragma unroll
  for (int k = 0; k < 8; ++k) {
    const float nv = f[k] * inv;
    const _Float16 hi = (_Float16)nv;
    vh[k] = hi;
    vl[k] = (_Float16)(nv - (float)hi);
  }
  unsigned short* ph = y + (size_t)blockIdx.x * 512 + lane * 8;
  *(f16x8*)ph = vh;
  *(f16x8*)(ph + (size_t)loOff) = vl;
}

// ---------------------------------------------------------------- dense
__global__ __launch_bounds__(64) void dense_k(const float* __restrict__ r2,
                                              const float* __restrict__ wd,
                                              const float* __restrict__ bd,
                                              float* __restrict__ geo) {
  const int o = blockIdx.x;
  const int b = blockIdx.y;
  const int lane = threadIdx.x;
  const float* __restrict__ rb = r2 + (size_t)b * 2304;
  float s = 0.f;
  for (int k = lane; k < 2304; k += 64) s += rb[k] * wd[(size_t)k * 18 + o];
#pragma unroll
  for (int off = 32; off; off >>= 1) s += __shfl_xor(s, off, 64);
  if (lane == 0) geo[b * 18 + o] = s + bd[o];
}

// ---------------------------------------------------------------- TPS
// LDS-parallel version (R8). One block (1 wave) per batch.
__device__ __forceinline__ float tps_u(float r) { return r * r * logf(r + 1e-6f); }

__global__ __launch_bounds__(64) void tps_k(const float* __restrict__ geo,
                                            float* __restrict__ axb,
                                            float* __restrict__ ayb) {
  const int b = blockIdx.x;
  const int tid = threadIdx.x;
  __shared__ float M[12][14];
  __shared__ float fel[12];
  __shared__ float dxs[9], dys[9];
  __shared__ float th[2][12];   // [0]=x theta, [1]=y theta
  __shared__ float sW[2][9];
  __shared__ float sA[2][3];
  __shared__ int sPiv;

  const float srcx[9] = {0.f, 0.5f, 1.f, 0.f, 0.5f, 1.f, 0.f, 5.f, 1.f};
  const float srcy[9] = {0.f, 0.f, 0.f, 0.5f, 0.5f, 0.5f, 1.f, 1.f, 1.f};

  // dst points + RHS columns (12,13)
  if (tid < 9) {
    const float mx = geo[b * 18 + 2 * tid], my = geo[b * 18 + 2 * tid + 1];
    dxs[tid] = srcx[tid] + mx;
    dys[tid] = srcy[tid] + my;
    M[tid][12] = -mx;
    M[tid][13] = -my;
  } else if (tid < 12) {
    M[tid][12] = 0.f;
    M[tid][13] = 0.f;
  }
  __syncthreads();
  // K block: 81 tps_u entries in parallel
  for (int e = tid; e < 81; e += 64) {
    const int p = e / 9, q = e % 9;
    const float ddx = dxs[p] - dxs[q], ddy = dys[p] - dys[q];
    const float r = sqrtf(ddx * ddx + ddy * ddy + 1e-12f);
    M[p][q] = tps_u(r);
  }
  // P blocks + zero bottom-right 3x3
  if (tid < 9) {
    M[tid][9] = 1.f;  M[tid][10] = dxs[tid]; M[tid][11] = dys[tid];
    M[9][tid] = 1.f;  M[10][tid] = dxs[tid]; M[11][tid] = dys[tid];
  } else if (tid < 12) {
    M[tid][9] = 0.f; M[tid][10] = 0.f; M[tid][11] = 0.f;
  }
  __syncthreads();

  // Gaussian elimination with partial pivoting (same arithmetic/order as R7)
  for (int k = 0; k < 12; ++k) {
    if (tid == 0) {
      int piv = k;
      float best = fabsf(M[k][k]);
      for (int r = k + 1; r < 12; ++r) {
        const float v = fabsf(M[r][k]);
        if (v > best) { best = v; piv = r; }
      }
      sPiv = piv;
    }
    __syncthreads();
    const int piv = sPiv;
    if (piv != k && tid < 14) {
      const float tmp = M[k][tid];
      M[k][tid] = M[piv][tid];
      M[piv][tid] = tmp;
    }
    __syncthreads();
    if (tid > k && tid < 12) fel[tid] = M[tid][k] / M[k][k];
    __syncthreads();
    for (int e = tid; e < (11 - k) * 14; e += 64) {
      const int r = k + 1 + e / 14, cc = e % 14;
      if (cc >= k) M[r][cc] -= fel[r] * M[k][cc];
    }
    __syncthreads();
  }

  // Back substitution: lanes 0-15 -> x (RHS col 12), lanes 16-31 -> y (col 13)
  const int grp = tid >> 4;
  const int cc = tid & 15;
  for (int k = 11; k >= 0; --k) {
    float prod = 0.f;
    if (grp < 2 && cc > k && cc < 12) prod = M[k][cc] * th[grp][cc];
#pragma unroll
    for (int off = 8; off; off >>= 1) prod += __shfl_xor(prod, off, 16);
    if (grp < 2 && cc == 0) th[grp][k] = (M[k][12 + grp] - prod) / M[k][k];
    __syncthreads();
  }

  // w/a extraction: w[0] = -sum(theta[1..8]), w[p]=theta[p], a = theta[9..11]
  if (tid < 2) {
    float sw = 0.f;
    for (int p = 1; p < 9; ++p) {
      sW[tid][p] = th[tid][p];
      sw += th[tid][p];
    }
    sW[tid][0] = -sw;
    sA[tid][0] = th[tid][9];
    sA[tid][1] = th[tid][10];
    sA[tid][2] = th[tid][11];
  }
  __syncthreads();

  // evaluate warp field on the 16x16 grid (4 points per lane)
  for (int p = tid; p < 256; p += 64) {
    const int pi = p >> 4, pj = p & 15;
    const float x = pj * (1.f / 15.f), y = pi * (1.f / 15.f);
    float zx = sA[0][0] + x * sA[0][1] + y * sA[0][2];
    float zy = sA[1][0] + x * sA[1][1] + y * sA[1][2];
#pragma unroll
    for (int c = 0; c < 9; ++c) {
      const float ddx = x - dxs[c], ddy = y - dys[c];
      const float r = sqrtf(ddx * ddx + ddy * ddy + 1e-12f);
      const float u = tps_u(r);
      zx += u * sW[0][c];
      zy += u * sW[1][c];
    }
    axb[b * 256 + p] = (x + zx) * 15.f;
    ayb[b * 256 + p] = (y + zy) * 15.f;
  }
}

// ---------------------------------------------------------------- masked sum
__global__ __launch_bounds__(256) void masksum_k(const float* __restrict__ corr,
                                                 const float* __restrict__ axb,
                                                 const float* __restrict__ ayb,
                                                 float* __restrict__ out) {
  const int b = blockIdx.x;
  const int pB = threadIdx.x;
  const float ax = axb[b * 256 + pB];
  const float ay = ayb[b * 256 + pB];
  const float* __restrict__ cb = corr + (size_t)b * 65536;
  float s = 0.f;
  for (int i = 0; i < 16; ++i) {
    if (fabsf((float)i - ay) <= 1.0f) {
      const float* __restrict__ ci = cb + (size_t)i * 16 * 256 + pB;
      for (int j = 0; j < 16; ++j) {
        if (fabsf((float)j - ax) <= 1.0f) s += ci[(size_t)j * 256];
      }
    }
  }
  __shared__ float sm[256];
  sm[pB] = s;
  __syncthreads();
  for (int off = 128; off; off >>= 1) {
    if (pB < off) sm[pB] += sm[pB + off];
    __syncthreads();
  }
  if (pB == 0) out[b] = sm[0];
}

// ---------------------------------------------------------------- launch
extern "C" void kernel_launch(void* const* d_in, const int* in_sizes, int n_in,
                              void* d_out, int out_size, void* d_ws, size_t ws_size,
                              hipStream_t stream) {
  const float* imgA = (const float*)d_in[0];
  const float* imgB = (const float*)d_in[1];
  const float* W1 = (const float*)d_in[2];
  const float* W2 = (const float*)d_in[3];
  const float* W3 = (const float*)d_in[4];
  const float* W4 = (const float*)d_in[5];
  const float* Wr1 = (const float*)d_in[6];
  const float* Wr2 = (const float*)d_in[7];
  const float* Wd = (const float*)d_in[8];
  const float* bd = (const float*)d_in[9];

  float* ws = (float*)d_ws;
  unsigned short* WT2 = (unsigned short*)(ws + 0);
  unsigned short* WT3 = (unsigned short*)(ws + 36864);
  unsigned short* WT4 = (unsigned short*)(ws + 184320);
  unsigned short* WTr1 = (unsigned short*)(ws + 774144);
  unsigned short* WTr2 = (unsigned short*)(ws + 1576960);
  unsigned short* FEATs = (unsigned short*)(ws + 1679360);
  unsigned short* S2 = (unsigned short*)(ws + 5873664);
  unsigned short* S1 = (unsigned short*)(ws + 14262272);
  unsigned short* S3 = (unsigned short*)(ws + 14262272);    // overlays S1
  unsigned short* FEATsp = (unsigned short*)(ws + 5873664); // overlays S2
  float* CORRf = ws + 14262272;                             // overlays S1/S3
  unsigned short* CORRh = (unsigned short*)(ws + 16359424);
  float* R1p = ws + 17408000;
  unsigned short* R1h = (unsigned short*)(ws + 20275200);
  float* R2p = ws + 20480000;
  float* R2f = ws + 22323200;
  float* GEOb = ws + 22396928;
  float* AXb = ws + 22397504;
  float* AYb = ws + 22405696;
  unsigned short* WT1 = (unsigned short*)(ws + 31039488);   // after S1 end

  // weight prep (all single-plane)
  wt1_prep<<<8, 256, 0, stream>>>(W1, WT1);
  wt_single<<<288, 256, 0, stream>>>(W2, WT2, 576, 128);
  wt_single<<<1152, 256, 0, stream>>>(W3, WT3, 1152, 256);
  wt_single<<<4608, 256, 0, stream>>>(W4, WT4, 2304, 512);
  wt_single<<<6272, 256, 0, stream>>>(Wr1, WTr1, 12544, 128);
  wt_single<<<800, 256, 0, stream>>>(Wr2, WTr2, 3200, 64);

  for (int img = 0; img < 2; ++img) {
    const float* src = img ? imgB : imgA;
    conv1_mfma<<<dim3(128, 32), 256, 0, stream>>>(src, WT1, S1);
    // conv2: M = 32*4096 = 131072 -> 1024 blocks of 128x128
    tile_conv<128, 128, 64, 128, 3, 3, 2, 1, 0, 1, 0, 0, 1>
        <<<dim3(1024, 1), 256, 0, stream>>>(S1, WT2, S2, nullptr,
                                            128, 128, 64, 64, 0, 0);
    // conv3: M = 32768 -> 256x2
    tile_conv<128, 128, 128, 256, 3, 3, 2, 1, 0, 1, 0, 0, 1>
        <<<dim3(256, 2), 256, 0, stream>>>(S2, WT3, S3, nullptr,
                                           64, 64, 32, 32, 0, 0);
    // conv4: M = 8192 -> 128x4 of 64x128
    tile_conv<64, 128, 256, 512, 3, 3, 2, 1, 0, 1, 0, 0, 1>
        <<<dim3(128, 4), 256, 0, stream>>>(S3, WT4, FEATs + (size_t)img * 4194304,
                                           nullptr, 32, 32, 16, 16, 0, 0);
  }

  // l2norm: FEATs (single) -> FEATsp (split pair, lo at +8388608 el)
  l2norm_k<<<16384, 64, 0, stream>>>(FEATs, FEATsp, 8388608);
  // corr: tiled split GEMM (batched B), fp32 out + single fp16 hi out
  tile_conv<64, 64, 512, 256, 1, 1, 1, 0, 1, 1, 1, 1, 0>
      <<<dim3(128, 4), 256, 0, stream>>>(FEATsp, FEATsp + 4194304, CORRh, CORRf,
                                         16, 16, 16, 16, 8388608, 8388608);
  // conv_r1: tiled single fp16, split-K 7 -> fp32 partials
  tile_conv<64, 128, 256, 128, 7, 7, 1, 0, 0, 7, 0, 0, 0>
      <<<dim3(50, 1, 7), 256, 0, stream>>>(CORRh, WTr1, nullptr, R1p,
                                           16, 16, 10, 10, 0, 0);
  sum_relu_s<<<1600, 256, 0, stream>>>(R1p, R1h, 409600, 7);
  // conv_r2: direct single fp16, split-K 25
  gemm_conv<1, 4, 128, 64, 5, 5, 25>
      <<<dim3(18, 1, 25), 256, 0, stream>>>(R1h, WTr2, R2p, 10, 10, 6, 6);
  sum_relu_f<<<288, 256, 0, stream>>>(R2p, R2f, 73728, 25);
  dense_k<<<dim3(18, 32), 64, 0, stream>>>(R2f, Wd, bd, GEOb);
  tps_k<<<32, 64, 0, stream>>>(GEOb, AXb, AYb);
  masksum_k<<<32, 256, 0, stream>>>(CORRf, AXb, AYb, (float*)d_out);
}

// Round 3
// 472.993 us; speedup vs baseline: 1.3745x; 1.0538x over previous
//
#include <hip/hip_runtime.h>
#include <math.h>

// ---------------------------------------------------------------------------
// Round 10: tile_conv -> double-buffered 2-phase pipeline (T3 minimal).
//   R9 tile_conv: 2 barriers + exposed global latency per 64-wide K-step ->
//   conv2 at 51us with MfmaUtil 13% / VALUBusy 12% / HBM 20% (all idle).
//   Now: LDS double-buffer, prefetch next K-chunk into regs before the
//   barrier, ONE barrier per iteration, ds_write of prefetched regs after
//   compute (vmcnt covered by compute phase). LDS 2x (73.7KB worst) -> 2
//   blocks/CU, fine given stall-dominated baseline.
//
//   conv1: conv1_mfma (R9, K=27->32 single MFMA).
//   tps_k: LDS-parallel Gaussian elimination (R8).
//   conv2/3/4: tile_conv single fp16; corr: tile_conv SPLIT (hi+lo, 3xMFMA)
//   conv_r1: tile_conv split-K 7; conv_r2: gemm_conv split-K 25.
//
// Workspace (float units), peak 124.16 MB (<127.8 MB proven round 5):
//   WT2@0(36864) WT3@36864(147456) WT4@184320(589824)
//   WTr1@774144(802816,single) WTr2@1576960(102400,single)
//   FEATs @1679360 (4194304)   single fp16, 2 img x 8192 x 512
//   S2    @5873664 (8388608)   full img 32x64x64x128 fp16
//   S1    @14262272 (16777216) full img 32x128x128x64 fp16
//   S3    overlays S1 @14262272 (4194304)
//   post-chain: FEATsp @5873664 (8388608, hi+lo; overlays S2)
//     CORRf@14262272(2097152) CORRh@16359424(1048576, single)
//     R1p@17408000(7x409600) R1h@20275200(204800, single)
//     R2p@20480000(25x73728) R2f@22323200(73728)
//     GEO@22396928 AX@22397504 AY@22405696 -> end 22413888
//   WT1@31039488 (1024)  -- after S1 end, avoids overlay collision
// ---------------------------------------------------------------------------

typedef __attribute__((ext_vector_type(8))) _Float16 f16x8;
typedef __attribute__((ext_vector_type(4))) float f32x4;

__device__ __forceinline__ unsigned short f2h(float f) {
  return __builtin_bit_cast(unsigned short, (_Float16)f);
}
__device__ __forceinline__ float h2f(unsigned short u) {
  return (float)__builtin_bit_cast(_Float16, u);
}

// ---------------------------------------------------------------- weight prep
__global__ __launch_bounds__(256) void wt_single(const float* __restrict__ w,
                                                 unsigned short* __restrict__ wt,
                                                 int K, int C) {
  const int idx = blockIdx.x * 256 + threadIdx.x;
  if (idx < K * C) {
    const int k = idx / C, o = idx % C;
    wt[(size_t)o * K + k] = f2h(w[idx]);
  }
}

// WT1: [64 out][32 k] fp16, k = (di*3+dj)*3+c for k<27, zero-padded to 32.
__global__ __launch_bounds__(256) void wt1_prep(const float* __restrict__ w,
                                                unsigned short* __restrict__ wt) {
  const int idx = blockIdx.x * 256 + threadIdx.x;  // 64*32 = 2048
  if (idx < 2048) {
    const int o = idx >> 5, k = idx & 31;
    wt[idx] = (k < 27) ? f2h(w[(size_t)k * 64 + o]) : (unsigned short)0;
  }
}

// ---------------------------------------------------------------- conv1 MFMA
// One block per (output row i, batch b). 256 threads = 4 waves.
// Wave w computes rows j = w*32..w*32+31 (MT=2) x all 64 channels (NT=4).
// K = 32 (27 real taps + 5 zero pad) -> single MFMA per 16x16 tile.
__global__ __launch_bounds__(256) void conv1_mfma(const float* __restrict__ in,
                                                  const unsigned short* __restrict__ wt1,
                                                  unsigned short* __restrict__ out) {
  const int i = blockIdx.x;   // output row 0..127
  const int b = blockIdx.y;   // batch 0..31
  const int tid = threadIdx.x;
  const int lane = tid & 63, wid = tid >> 6;
  const int lrow = lane & 15, quad = lane >> 4;

  // Rows[di][x*3+c], x in 0..256 (x=256 is SAME right-pad, zero)
  __shared__ _Float16 Rows[3][771];

  const float* __restrict__ inb = in + (size_t)b * 196608;  // 256*256*3
#pragma unroll
  for (int di = 0; di < 3; ++di) {
    const int y = 2 * i + di;
    if (y < 256) {
      const float* __restrict__ row = inb + (size_t)y * 768;
      for (int e = tid; e < 768; e += 256) Rows[di][e] = (_Float16)row[e];
    } else {
      for (int e = tid; e < 768; e += 256) Rows[di][e] = (_Float16)0.f;
    }
    if (tid < 3) Rows[di][768 + tid] = (_Float16)0.f;
  }
  __syncthreads();

  // B fragments: all 64 cols, straight from WT1[64][32]
  f16x8 bf[4];
#pragma unroll
  for (int ni = 0; ni < 4; ++ni)
    bf[ni] = *(const f16x8*)(wt1 + (ni * 16 + lrow) * 32 + quad * 8);

  // A fragments: im2col gather from staged rows.
  // k = (di*3+dj)*3 + c -> di=k/9, dj=(k/3)%3, c=k%3
  f16x8 af[2];
#pragma unroll
  for (int mi = 0; mi < 2; ++mi) {
    const int j = wid * 32 + mi * 16 + lrow;
#pragma unroll
    for (int s = 0; s < 8; ++s) {
      const int k = quad * 8 + s;
      if (k < 27) {
        const int di = k / 9, dj = (k / 3) % 3, c = k % 3;
        af[mi][s] = Rows[di][(2 * j + dj) * 3 + c];
      } else {
        af[mi][s] = (_Float16)0.f;
      }
    }
  }

  f32x4 acc[2][4];
#pragma unroll
  for (int mi = 0; mi < 2; ++mi)
#pragma unroll
    for (int ni = 0; ni < 4; ++ni) {
      const f32x4 z = {0.f, 0.f, 0.f, 0.f};
      acc[mi][ni] = __builtin_amdgcn_mfma_f32_16x16x32_f16(af[mi], bf[ni], z, 0, 0, 0);
    }

  // epilogue: row = quad*4+r, col = lrow (tile_conv layout), fused ReLU
  unsigned short* __restrict__ ob = out + (((size_t)b * 128 + i) * 128) * 64;
#pragma unroll
  for (int mi = 0; mi < 2; ++mi)
#pragma unroll
    for (int ni = 0; ni < 4; ++ni)
#pragma unroll
      for (int r = 0; r < 4; ++r) {
        const int j = wid * 32 + mi * 16 + quad * 4 + r;
        const int col = ni * 16 + lrow;
        ob[(size_t)j * 64 + col] = f2h(fmaxf(acc[mi][ni][r], 0.f));
      }
}

// ---------------------------------------------------------------- tile conv
// LDS-tiled implicit-GEMM, DOUBLE-BUFFERED 2-phase (R10):
//   prologue: load chunk0 -> regs -> LDS buf0
//   loop: prefetch chunk+1 -> regs; barrier; ds_read buf[cur] + MFMA;
//         write regs -> buf[cur^1].  ONE barrier/iter, latency hidden.
// SPLIT: A/B have hi+lo planes (aLo/bLo el offsets), 3 MFMAs per pair.
// SK>1: split-K over taps, fp32 partial slices to outf.
// BATB: B rows batched by A's batch index (corr).
// OUTF32: write fp32 to outf AND single fp16 hi to outh.
template <int BM, int BN, int CIN, int COUT, int KH, int KW, int STRIDE,
          int SAMEPAD, int SPLIT, int SK, int BATB, int OUTF32, int RELU>
__global__ __launch_bounds__(256) void tile_conv(
    const unsigned short* __restrict__ in, const unsigned short* __restrict__ wt,
    unsigned short* __restrict__ outh, float* __restrict__ outf,
    int Hin, int Win, int Hout, int Wout, int aLo, int bLo) {
  constexpr int LDA = 72;
  constexpr int CPT = CIN / 64;
  constexpr int LA = BM / 32;
  constexpr int LB = BN / 32;
  constexpr int KTOT = KH * KW * CIN;
  constexpr int MT = BM / 32;
  constexpr int NT = BN / 32;
  __shared__ _Float16 As[2][(1 + SPLIT) * BM * LDA];
  __shared__ _Float16 Bs[2][(1 + SPLIT) * BN * LDA];

  const int t = threadIdx.x;
  const int lane = t & 63, wid = t >> 6;
  const int lrow = lane & 15, quad = lane >> 4;
  const int m0 = blockIdx.x * BM;
  const int n0 = blockIdx.y * BN;

  int pixB[LA], iS[LA], jS[LA], lofA[LA];
#pragma unroll
  for (int i = 0; i < LA; ++i) {
    const int u = t + 256 * i;
    const int r = u >> 3, sl = u & 7;
    const int m = m0 + r;
    const int j = m % Wout;
    const int t2 = m / Wout;
    const int ii = t2 % Hout;
    const int b = t2 / Hout;
    iS[i] = ii * STRIDE;
    jS[i] = j * STRIDE;
    pixB[i] = ((b * Hin + iS[i]) * Win + jS[i]) * CIN + sl * 8;
    lofA[i] = r * LDA + sl * 8;
  }
  const unsigned short* wb = wt;
  if (BATB) wb += (size_t)(m0 / (Hout * Wout)) * COUT * KTOT;
  int bofB[LB], lofB[LB];
#pragma unroll
  for (int i = 0; i < LB; ++i) {
    const int u = t + 256 * i;
    const int r = u >> 3, sl = u & 7;
    bofB[i] = (n0 + r) * KTOT + sl * 8;
    lofB[i] = r * LDA + sl * 8;
  }

  const f16x8 zh = {0, 0, 0, 0, 0, 0, 0, 0};
  f32x4 acc[MT][NT];
#pragma unroll
  for (int mi = 0; mi < MT; ++mi)
#pragma unroll
    for (int ni = 0; ni < NT; ++ni) acc[mi][ni] = {0.f, 0.f, 0.f, 0.f};

  const int mB = (wid >> 1) * (BM / 2);
  const int nB = (wid & 1) * (BN / 2);

  int tap_lo = 0, tap_hi = KH * KW;
  if (SK > 1) {
    tap_lo = (int)blockIdx.z * KH * KW / SK;
    tap_hi = ((int)blockIdx.z + 1) * KH * KW / SK;
  }
  const int ch_lo = tap_lo * CPT, ch_hi = tap_hi * CPT;

  f16x8 va[LA], vb[LB], va2[LA], vb2[LB];

  auto load_ch = [&](int ch) {
    const int tap = ch / CPT;
    const int c0 = (ch % CPT) * 64;
    const int di = tap / KW, dj = tap % KW;
    const int toff = (di * Win + dj) * CIN + c0;
    const int woff = tap * CIN + c0;
#pragma unroll
    for (int i = 0; i < LA; ++i) {
      const bool ok = !SAMEPAD || ((iS[i] + di < Hin) && (jS[i] + dj < Win));
      va[i] = ok ? *(const f16x8*)(in + pixB[i] + toff) : zh;
      if (SPLIT) va2[i] = ok ? *(const f16x8*)(in + pixB[i] + toff + aLo) : zh;
    }
#pragma unroll
    for (int i = 0; i < LB; ++i) {
      vb[i] = *(const f16x8*)(wb + bofB[i] + woff);
      if (SPLIT) vb2[i] = *(const f16x8*)(wb + bofB[i] + woff + bLo);
    }
  };
  auto write_buf = [&](int buf) {
#pragma unroll
    for (int i = 0; i < LA; ++i) {
      *(f16x8*)&As[buf][lofA[i]] = va[i];
      if (SPLIT) *(f16x8*)&As[buf][BM * LDA + lofA[i]] = va2[i];
    }
#pragma unroll
    for (int i = 0; i < LB; ++i) {
      *(f16x8*)&Bs[buf][lofB[i]] = vb[i];
      if (SPLIT) *(f16x8*)&Bs[buf][BN * LDA + lofB[i]] = vb2[i];
    }
  };

  load_ch(ch_lo);
  write_buf(0);
  int cur = 0;
  for (int ch = ch_lo; ch < ch_hi; ++ch) {
    const bool hasNext = (ch + 1 < ch_hi);
    if (hasNext) load_ch(ch + 1);   // prefetch issues before the barrier
    __syncthreads();                // buf[cur] ready (writes of prev iter)
#pragma unroll
    for (int ks = 0; ks < 2; ++ks) {
      f16x8 af[MT], bf[NT], al[MT], bl[NT];
#pragma unroll
      for (int mi = 0; mi < MT; ++mi) {
        const int off = (mB + mi * 16 + lrow) * LDA + ks * 32 + quad * 8;
        af[mi] = *(const f16x8*)&As[cur][off];
        if (SPLIT) al[mi] = *(const f16x8*)&As[cur][BM * LDA + off];
      }
#pragma unroll
      for (int ni = 0; ni < NT; ++ni) {
        const int off = (nB + ni * 16 + lrow) * LDA + ks * 32 + quad * 8;
        bf[ni] = *(const f16x8*)&Bs[cur][off];
        if (SPLIT) bl[ni] = *(const f16x8*)&Bs[cur][BN * LDA + off];
      }
#pragma unroll
      for (int mi = 0; mi < MT; ++mi)
#pragma unroll
        for (int ni = 0; ni < NT; ++ni) {
          if (SPLIT) {
            acc[mi][ni] = __builtin_amdgcn_mfma_f32_16x16x32_f16(af[mi], bl[ni],
                                                                 acc[mi][ni], 0, 0, 0);
            acc[mi][ni] = __builtin_amdgcn_mfma_f32_16x16x32_f16(al[mi], bf[ni],
                                                                 acc[mi][ni], 0, 0, 0);
          }
          acc[mi][ni] = __builtin_amdgcn_mfma_f32_16x16x32_f16(af[mi], bf[ni],
                                                               acc[mi][ni], 0, 0, 0);
        }
    }
    if (hasNext) write_buf(cur ^ 1);  // no conflict with buf[cur] readers
    cur ^= 1;
  }
  const size_t slice =
      (SK > 1) ? (size_t)blockIdx.z * ((size_t)gridDim.x * BM * COUT) : 0;
#pragma unroll
  for (int mi = 0; mi < MT; ++mi)
#pragma unroll
    for (int ni = 0; ni < NT; ++ni)
#pragma unroll
      for (int r = 0; r < 4; ++r) {
        const int row = m0 + mB + mi * 16 + quad * 4 + r;
        const int col = n0 + nB + ni * 16 + lrow;
        const size_t idx = (size_t)row * COUT + col;
        float v = acc[mi][ni][r];
        if (SK > 1) {
          outf[slice + idx] = v;
        } else if (OUTF32) {
          outf[idx] = v;
          outh[idx] = f2h(v);
        } else {
          if (RELU) v = fmaxf(v, 0.f);
          outh[idx] = f2h(v);
        }
      }
}

// ---------------------------------------------------------------- direct MFMA
// kept for conv_r2 (tiny), single plane.
template <int MT, int NT, int CIN, int COUT, int KH, int KW, int SK>
__global__ __launch_bounds__(256) void gemm_conv(
    const unsigned short* __restrict__ in, const unsigned short* __restrict__ wt,
    float* __restrict__ outf, int Hin, int Win, int Hout, int Wout) {
  const int KTOT = KH * KW * CIN;
  const int lane = threadIdx.x & 63;
  const int wid = threadIdx.x >> 6;
  const int lrow = lane & 15;
  const int quad = lane >> 4;
  const int m0 = (blockIdx.x * 4 + wid) * (16 * MT);
  const int n0 = blockIdx.y * (16 * NT);

  int pix[MT];
#pragma unroll
  for (int mi = 0; mi < MT; ++mi) {
    const int m = m0 + mi * 16 + lrow;
    const int j = m % Wout;
    const int t = m / Wout;
    const int i = t % Hout;
    const int b = t / Hout;
    pix[mi] = (b * Hin + i) * Win + j;
  }
  const unsigned short* brow[NT];
#pragma unroll
  for (int ni = 0; ni < NT; ++ni)
    brow[ni] = wt + (size_t)(n0 + ni * 16 + lrow) * KTOT + quad * 8;

  f32x4 acc[MT][NT];
#pragma unroll
  for (int mi = 0; mi < MT; ++mi)
#pragma unroll
    for (int ni = 0; ni < NT; ++ni) acc[mi][ni] = {0.f, 0.f, 0.f, 0.f};

  const int tap_lo = (int)blockIdx.z * KH * KW / SK;
  const int tap_hi = ((int)blockIdx.z + 1) * KH * KW / SK;
  for (int tap = tap_lo; tap < tap_hi; ++tap) {
    const int di = tap / KW, dj = tap % KW;
    const unsigned short* ap[MT];
#pragma unroll
    for (int mi = 0; mi < MT; ++mi)
      ap[mi] = in + ((size_t)pix[mi] + di * Win + dj) * CIN + quad * 8;
    const int ko = tap * CIN;
#pragma unroll
    for (int c0 = 0; c0 < CIN; c0 += 32) {
      f16x8 ah[MT], bh[NT];
#pragma unroll
      for (int mi = 0; mi < MT; ++mi) ah[mi] = *(const f16x8*)(ap[mi] + c0);
#pragma unroll
      for (int ni = 0; ni < NT; ++ni) bh[ni] = *(const f16x8*)(brow[ni] + ko + c0);
#pragma unroll
      for (int mi = 0; mi < MT; ++mi)
#pragma unroll
        for (int ni = 0; ni < NT; ++ni)
          acc[mi][ni] = __builtin_amdgcn_mfma_f32_16x16x32_f16(ah[mi], bh[ni],
                                                               acc[mi][ni], 0, 0, 0);
    }
  }
  const size_t slice = (size_t)blockIdx.z * ((size_t)gridDim.x * 64 * MT * COUT);
#pragma unroll
  for (int mi = 0; mi < MT; ++mi)
#pragma unroll
    for (int ni = 0; ni < NT; ++ni)
#pragma unroll
      for (int r = 0; r < 4; ++r) {
        const int row = m0 + mi * 16 + quad * 4 + r;
        const int col = n0 + ni * 16 + lrow;
        outf[slice + (size_t)row * COUT + col] = acc[mi][ni][r];
      }
}

// ---------------------------------------------------------------- split-K epi
__global__ __launch_bounds__(256) void sum_relu_s(const float* __restrict__ p,
                                                  unsigned short* __restrict__ o,
                                                  int n, int parts) {
  const int idx = blockIdx.x * 256 + threadIdx.x;
  if (idx < n) {
    float v = 0.f;
    for (int s = 0; s < parts; ++s) v += p[(size_t)s * n + idx];
    o[idx] = f2h(fmaxf(v, 0.f));
  }
}
__global__ __launch_bounds__(256) void sum_relu_f(const float* __restrict__ p,
                                                  float* __restrict__ o,
                                                  int n, int parts) {
  const int idx = blockIdx.x * 256 + threadIdx.x;
  if (idx < n) {
    float v = 0.f;
    for (int s = 0; s < parts; ++s) v += p[(size_t)s * n + idx];
    o[idx] = fmaxf(v, 0.f);
  }
}

// ---------------------------------------------------------------- l2 normalize
// in: single fp16; out: split pair (hi @y, lo @y+loOff).
__global__ __launch_bounds__(64) void l2norm_k(const unsigned short* __restrict__ x,
                                               unsigned short* __restrict__ y,
                                               int loOff) {
  const int lane = threadIdx.x;
  const f16x8 v = *(const f16x8*)(x + (size_t)blockIdx.x * 512 + lane * 8);
  float f[8];
  float s = 0.f;
#pragma unroll
  for (int k = 0; k < 8; ++k) {
    f[k] = (float)v[k];
    s += f[k] * f[k];
  }
#pragma unroll
  for (int off = 32; off; off >>= 1) s += __shfl_xor(s, off, 64);
  const float inv = 1.f / (sqrtf(s) + 1e-6f);
  f16x8 vh, vl;
#pragma unroll
  for (int k = 0; k < 8; ++k) {
    const float nv = f[k] * inv;
    const _Float16 hi = (_Float16)nv;
    vh[k] = hi;
    vl[k] = (_Float16)(nv - (float)hi);
  }
  unsigned short* ph = y + (size_t)blockIdx.x * 512 + lane * 8;
  *(f16x8*)ph = vh;
  *(f16x8*)(ph + (size_t)loOff) = vl;
}

// ---------------------------------------------------------------- dense
__global__ __launch_bounds__(64) void dense_k(const float* __restrict__ r2,
                                              const float* __restrict__ wd,
                                              const float* __restrict__ bd,
                                              float* __restrict__ geo) {
  const int o = blockIdx.x;
  const int b = blockIdx.y;
  const int lane = threadIdx.x;
  const float* __restrict__ rb = r2 + (size_t)b * 2304;
  float s = 0.f;
  for (int k = lane; k < 2304; k += 64) s += rb[k] * wd[(size_t)k * 18 + o];
#pragma unroll
  for (int off = 32; off; off >>= 1) s += __shfl_xor(s, off, 64);
  if (lane == 0) geo[b * 18 + o] = s + bd[o];
}

// ---------------------------------------------------------------- TPS
// LDS-parallel version (R8). One block (1 wave) per batch.
__device__ __forceinline__ float tps_u(float r) { return r * r * logf(r + 1e-6f); }

__global__ __launch_bounds__(64) void tps_k(const float* __restrict__ geo,
                                            float* __restrict__ axb,
                                            float* __restrict__ ayb) {
  const int b = blockIdx.x;
  const int tid = threadIdx.x;
  __shared__ float M[12][14];
  __shared__ float fel[12];
  __shared__ float dxs[9], dys[9];
  __shared__ float th[2][12];   // [0]=x theta, [1]=y theta
  __shared__ float sW[2][9];
  __shared__ float sA[2][3];
  __shared__ int sPiv;

  const float srcx[9] = {0.f, 0.5f, 1.f, 0.f, 0.5f, 1.f, 0.f, 5.f, 1.f};
  const float srcy[9] = {0.f, 0.f, 0.f, 0.5f, 0.5f, 0.5f, 1.f, 1.f, 1.f};

  // dst points + RHS columns (12,13)
  if (tid < 9) {
    const float mx = geo[b * 18 + 2 * tid], my = geo[b * 18 + 2 * tid + 1];
    dxs[tid] = srcx[tid] + mx;
    dys[tid] = srcy[tid] + my;
    M[tid][12] = -mx;
    M[tid][13] = -my;
  } else if (tid < 12) {
    M[tid][12] = 0.f;
    M[tid][13] = 0.f;
  }
  __syncthreads();
  // K block: 81 tps_u entries in parallel
  for (int e = tid; e < 81; e += 64) {
    const int p = e / 9, q = e % 9;
    const float ddx = dxs[p] - dxs[q], ddy = dys[p] - dys[q];
    const float r = sqrtf(ddx * ddx + ddy * ddy + 1e-12f);
    M[p][q] = tps_u(r);
  }
  // P blocks + zero bottom-right 3x3
  if (tid < 9) {
    M[tid][9] = 1.f;  M[tid][10] = dxs[tid]; M[tid][11] = dys[tid];
    M[9][tid] = 1.f;  M[10][tid] = dxs[tid]; M[11][tid] = dys[tid];
  } else if (tid < 12) {
    M[tid][9] = 0.f; M[tid][10] = 0.f; M[tid][11] = 0.f;
  }
  __syncthreads();

  // Gaussian elimination with partial pivoting (same arithmetic/order as R7)
  for (int k = 0; k < 12; ++k) {
    if (tid == 0) {
      int piv = k;
      float best = fabsf(M[k][k]);
      for (int r = k + 1; r < 12; ++r) {
        const float v = fabsf(M[r][k]);
        if (v > best) { best = v; piv = r; }
      }
      sPiv = piv;
    }
    __syncthreads();
    const int piv = sPiv;
    if (piv != k && tid < 14) {
      const float tmp = M[k][tid];
      M[k][tid] = M[piv][tid];
      M[piv][tid] = tmp;
    }
    __syncthreads();
    if (tid > k && tid < 12) fel[tid] = M[tid][k] / M[k][k];
    __syncthreads();
    for (int e = tid; e < (11 - k) * 14; e += 64) {
      const int r = k + 1 + e / 14, cc = e % 14;
      if (cc >= k) M[r][cc] -= fel[r] * M[k][cc];
    }
    __syncthreads();
  }

  // Back substitution: lanes 0-15 -> x (RHS col 12), lanes 16-31 -> y (col 13)
  const int grp = tid >> 4;
  const int cc = tid & 15;
  for (int k = 11; k >= 0; --k) {
    float prod = 0.f;
    if (grp < 2 && cc > k && cc < 12) prod = M[k][cc] * th[grp][cc];
#pragma unroll
    for (int off = 8; off; off >>= 1) prod += __shfl_xor(prod, off, 16);
    if (grp < 2 && cc == 0) th[grp][k] = (M[k][12 + grp] - prod) / M[k][k];
    __syncthreads();
  }

  // w/a extraction: w[0] = -sum(theta[1..8]), w[p]=theta[p], a = theta[9..11]
  if (tid < 2) {
    float sw = 0.f;
    for (int p = 1; p < 9; ++p) {
      sW[tid][p] = th[tid][p];
      sw += th[tid][p];
    }
    sW[tid][0] = -sw;
    sA[tid][0] = th[tid][9];
    sA[tid][1] = th[tid][10];
    sA[tid][2] = th[tid][11];
  }
  __syncthreads();

  // evaluate warp field on the 16x16 grid (4 points per lane)
  for (int p = tid; p < 256; p += 64) {
    const int pi = p >> 4, pj = p & 15;
    const float x = pj * (1.f / 15.f), y = pi * (1.f / 15.f);
    float zx = sA[0][0] + x * sA[0][1] + y * sA[0][2];
    float zy = sA[1][0] + x * sA[1][1] + y * sA[1][2];
#pragma unroll
    for (int c = 0; c < 9; ++c) {
      const float ddx = x - dxs[c], ddy = y - dys[c];
      const float r = sqrtf(ddx * ddx + ddy * ddy + 1e-12f);
      const float u = tps_u(r);
      zx += u * sW[0][c];
      zy += u * sW[1][c];
    }
    axb[b * 256 + p] = (x + zx) * 15.f;
    ayb[b * 256 + p] = (y + zy) * 15.f;
  }
}

// ---------------------------------------------------------------- masked sum
__global__ __launch_bounds__(256) void masksum_k(const float* __restrict__ corr,
                                                 const float* __restrict__ axb,
                                                 const float* __restrict__ ayb,
                                                 float* __restrict__ out) {
  const int b = blockIdx.x;
  const int pB = threadIdx.x;
  const float ax = axb[b * 256 + pB];
  const float ay = ayb[b * 256 + pB];
  const float* __restrict__ cb = corr + (size_t)b * 65536;
  float s = 0.f;
  for (int i = 0; i < 16; ++i) {
    if (fabsf((float)i - ay) <= 1.0f) {
      const float* __restrict__ ci = cb + (size_t)i * 16 * 256 + pB;
      for (int j = 0; j < 16; ++j) {
        if (fabsf((float)j - ax) <= 1.0f) s += ci[(size_t)j * 256];
      }
    }
  }
  __shared__ float sm[256];
  sm[pB] = s;
  __syncthreads();
  for (int off = 128; off; off >>= 1) {
    if (pB < off) sm[pB] += sm[pB + off];
    __syncthreads();
  }
  if (pB == 0) out[b] = sm[0];
}

// ---------------------------------------------------------------- launch
extern "C" void kernel_launch(void* const* d_in, const int* in_sizes, int n_in,
                              void* d_out, int out_size, void* d_ws, size_t ws_size,
                              hipStream_t stream) {
  const float* imgA = (const float*)d_in[0];
  const float* imgB = (const float*)d_in[1];
  const float* W1 = (const float*)d_in[2];
  const float* W2 = (const float*)d_in[3];
  const float* W3 = (const float*)d_in[4];
  const float* W4 = (const float*)d_in[5];
  const float* Wr1 = (const float*)d_in[6];
  const float* Wr2 = (const float*)d_in[7];
  const float* Wd = (const float*)d_in[8];
  const float* bd = (const float*)d_in[9];

  float* ws = (float*)d_ws;
  unsigned short* WT2 = (unsigned short*)(ws + 0);
  unsigned short* WT3 = (unsigned short*)(ws + 36864);
  unsigned short* WT4 = (unsigned short*)(ws + 184320);
  unsigned short* WTr1 = (unsigned short*)(ws + 774144);
  unsigned short* WTr2 = (unsigned short*)(ws + 1576960);
  unsigned short* FEATs = (unsigned short*)(ws + 1679360);
  unsigned short* S2 = (unsigned short*)(ws + 5873664);
  unsigned short* S1 = (unsigned short*)(ws + 14262272);
  unsigned short* S3 = (unsigned short*)(ws + 14262272);    // overlays S1
  unsigned short* FEATsp = (unsigned short*)(ws + 5873664); // overlays S2
  float* CORRf = ws + 14262272;                             // overlays S1/S3
  unsigned short* CORRh = (unsigned short*)(ws + 16359424);
  float* R1p = ws + 17408000;
  unsigned short* R1h = (unsigned short*)(ws + 20275200);
  float* R2p = ws + 20480000;
  float* R2f = ws + 22323200;
  float* GEOb = ws + 22396928;
  float* AXb = ws + 22397504;
  float* AYb = ws + 22405696;
  unsigned short* WT1 = (unsigned short*)(ws + 31039488);   // after S1 end

  // weight prep (all single-plane)
  wt1_prep<<<8, 256, 0, stream>>>(W1, WT1);
  wt_single<<<288, 256, 0, stream>>>(W2, WT2, 576, 128);
  wt_single<<<1152, 256, 0, stream>>>(W3, WT3, 1152, 256);
  wt_single<<<4608, 256, 0, stream>>>(W4, WT4, 2304, 512);
  wt_single<<<6272, 256, 0, stream>>>(Wr1, WTr1, 12544, 128);
  wt_single<<<800, 256, 0, stream>>>(Wr2, WTr2, 3200, 64);

  for (int img = 0; img < 2; ++img) {
    const float* src = img ? imgB : imgA;
    conv1_mfma<<<dim3(128, 32), 256, 0, stream>>>(src, WT1, S1);
    // conv2: M = 32*4096 = 131072 -> 1024 blocks of 128x128
    tile_conv<128, 128, 64, 128, 3, 3, 2, 1, 0, 1, 0, 0, 1>
        <<<dim3(1024, 1), 256, 0, stream>>>(S1, WT2, S2, nullptr,
                                            128, 128, 64, 64, 0, 0);
    // conv3: M = 32768 -> 256x2
    tile_conv<128, 128, 128, 256, 3, 3, 2, 1, 0, 1, 0, 0, 1>
        <<<dim3(256, 2), 256, 0, stream>>>(S2, WT3, S3, nullptr,
                                           64, 64, 32, 32, 0, 0);
    // conv4: M = 8192 -> 128x4 of 64x128
    tile_conv<64, 128, 256, 512, 3, 3, 2, 1, 0, 1, 0, 0, 1>
        <<<dim3(128, 4), 256, 0, stream>>>(S3, WT4, FEATs + (size_t)img * 4194304,
                                           nullptr, 32, 32, 16, 16, 0, 0);
  }

  // l2norm: FEATs (single) -> FEATsp (split pair, lo at +8388608 el)
  l2norm_k<<<16384, 64, 0, stream>>>(FEATs, FEATsp, 8388608);
  // corr: tiled split GEMM (batched B), fp32 out + single fp16 hi out
  tile_conv<64, 64, 512, 256, 1, 1, 1, 0, 1, 1, 1, 1, 0>
      <<<dim3(128, 4), 256, 0, stream>>>(FEATsp, FEATsp + 4194304, CORRh, CORRf,
                                         16, 16, 16, 16, 8388608, 8388608);
  // conv_r1: tiled single fp16, split-K 7 -> fp32 partials
  tile_conv<64, 128, 256, 128, 7, 7, 1, 0, 0, 7, 0, 0, 0>
      <<<dim3(50, 1, 7), 256, 0, stream>>>(CORRh, WTr1, nullptr, R1p,
                                           16, 16, 10, 10, 0, 0);
  sum_relu_s<<<1600, 256, 0, stream>>>(R1p, R1h, 409600, 7);
  // conv_r2: direct single fp16, split-K 25
  gemm_conv<1, 4, 128, 64, 5, 5, 25>
      <<<dim3(18, 1, 25), 256, 0, stream>>>(R1h, WTr2, R2p, 10, 10, 6, 6);
  sum_relu_f<<<288, 256, 0, stream>>>(R2p, R2f, 73728, 25);
  dense_k<<<dim3(18, 32), 64, 0, stream>>>(R2f, Wd, bd, GEOb);
  tps_k<<<32, 64, 0, stream>>>(GEOb, AXb, AYb);
  masksum_k<<<32, 256, 0, stream>>>(CORRf, AXb, AYb, (float*)d_out);
}